// Round 6
// baseline (321.077 us; speedup 1.0000x reference)
//
#include <hip/hip_runtime.h>
#include <hip/hip_fp16.h>

// Problem constants
static constexpr int NN   = 50000;
static constexpr int EE   = 800000;
static constexpr int GG   = 256;
static constexpr int PCH  = 16;                 // pooling chunks per graph
static constexpr int BK   = 128;                // targets per bucket
static constexpr int NB   = (NN + BK - 1) / BK; // 391 buckets (bucket = dst>>7)
static constexpr int CAP  = 4096;               // bucket region capacity (mean 2048, sigma 45)
static constexpr int CH   = 2048;               // edges per binA block
static constexpr int ABLK = (EE + CH - 1) / CH; // 391

typedef _Float16 f16;
typedef f16  f16x8 __attribute__((ext_vector_type(8)));
typedef float f32x4 __attribute__((ext_vector_type(4)));

// ---------- helpers ----------
__device__ __forceinline__ int lowerb(const int* __restrict__ b, int n, int v) {
    int lo = 0, hi = n;
    while (lo < hi) { int m = (lo + hi) >> 1; if (b[m] < v) lo = m + 1; else hi = m; }
    return lo;
}

// ---------- CSR build ----------
__global__ void init_k(int* __restrict__ bcur)
{
    int b = blockIdx.x * 256 + threadIdx.x;
    if (b < NB) bcur[b] = b * CAP;
}

// Pass A: partition edges into fixed-capacity bucket regions, coalesced flush.
__global__ __launch_bounds__(512) void binA_k(const int* __restrict__ ei,
                                              int* __restrict__ bcur,
                                              int2* __restrict__ eraw)
{
    __shared__ int2  stage[CH];
    __shared__ short sbid[CH];
    __shared__ int   hist[NB], loff[NB], gbase[NB], lcur[NB];
    __shared__ int   sc[512];

    int tid = threadIdx.x;
    int e0 = blockIdx.x * CH;
    int n = EE - e0; if (n > CH) n = CH;

    for (int b = tid; b < NB; b += 512) hist[b] = 0;
    __syncthreads();

    int2 r[CH / 512];
    #pragma unroll
    for (int k = 0; k < CH / 512; k++) {
        int s = k * 512 + tid;
        if (s < n) {
            int src = ei[e0 + s];
            int dst = ei[EE + e0 + s];
            r[k] = make_int2(src, dst);
            atomicAdd(&hist[dst >> 7], 1);
        }
    }
    __syncthreads();
    int v = (tid < NB) ? hist[tid] : 0;
    sc[tid] = v;
    __syncthreads();
    #pragma unroll
    for (int off = 1; off < 512; off <<= 1) {
        int add = (tid >= off) ? sc[tid - off] : 0;
        __syncthreads();
        sc[tid] += add;
        __syncthreads();
    }
    if (tid < NB) { int ex = sc[tid] - v; loff[tid] = ex; lcur[tid] = ex; }
    __syncthreads();
    for (int b = tid; b < NB; b += 512)
        gbase[b] = atomicAdd(&bcur[b], hist[b]);
    __syncthreads();
    #pragma unroll
    for (int k = 0; k < CH / 512; k++) {
        int s = k * 512 + tid;
        if (s < n) {
            int b = r[k].y >> 7;
            int slot = atomicAdd(&lcur[b], 1);
            stage[slot] = r[k];
            sbid[slot]  = (short)b;
        }
    }
    __syncthreads();
    for (int s = tid; s < n; s += 512) {
        int b = sbid[s];
        eraw[(size_t)gbase[b] + (s - loff[b])] = stage[s];
    }
}

// scan bucket totals -> bucket base offsets; rowptr[NN]=EE
__global__ __launch_bounds__(512) void scanb2_k(const int* __restrict__ bcur,
                                                int* __restrict__ bbase,
                                                int* __restrict__ rowptr)
{
    __shared__ int s[512];
    int t = threadIdx.x;
    int v = (t < NB) ? (bcur[t] - t * CAP) : 0;
    s[t] = v;
    __syncthreads();
    #pragma unroll
    for (int off = 1; off < 512; off <<= 1) {
        int add = (t >= off) ? s[t - off] : 0;
        __syncthreads();
        s[t] += add;
        __syncthreads();
    }
    if (t < NB) bbase[t] = s[t] - v;
    if (t == 0) rowptr[NN] = EE;
}

// Pass B: per bucket: LDS hist -> rowptr, place src ints at exact CSR slots
__global__ __launch_bounds__(512) void binB_k(const int2* __restrict__ eraw,
                                              const int* __restrict__ bcur,
                                              const int* __restrict__ bbase,
                                              int* __restrict__ rowptr,
                                              int* __restrict__ ebuf)
{
    __shared__ int hist[BK], excl[BK], cur[BK];
    int b = blockIdx.x, tid = threadIdx.x;
    int t0 = b << 7;
    int lim = NN - t0; if (lim > BK) lim = BK;
    int tot  = bcur[b] - b * CAP;
    int base = bbase[b];
    const int2* er = eraw + (size_t)b * CAP;

    if (tid < BK) hist[tid] = 0;
    __syncthreads();
    for (int s = tid; s < tot; s += 512) atomicAdd(&hist[er[s].y & 127], 1);
    __syncthreads();
    if (tid < BK) excl[tid] = hist[tid];
    __syncthreads();
    #pragma unroll
    for (int off = 1; off < BK; off <<= 1) {
        int add = (tid >= off && tid < BK) ? excl[tid - off] : 0;
        __syncthreads();
        if (tid < BK) excl[tid] += add;
        __syncthreads();
    }
    if (tid < BK) {
        int ex = excl[tid] - hist[tid];
        cur[tid] = base + ex;
        if (tid < lim) rowptr[t0 + tid] = base + ex;
    }
    __syncthreads();
    for (int s = tid; s < tot; s += 512) {
        int2 rec = er[s];
        int p = atomicAdd(&cur[rec.y & 127], 1);
        ebuf[p] = rec.x;
    }
}

// dinv from rowptr degree (+1 self-loop)
__global__ void dinv_k(const int* __restrict__ rowptr, float* __restrict__ dinv)
{
    int i = blockIdx.x * 256 + threadIdx.x;
    if (i < NN) dinv[i] = rsqrtf((float)(rowptr[i + 1] - rowptr[i] + 1));
}

// edge-parallel: ebuf2[e] = {batch[src], dinv[src]}
__global__ void pbb_k(const int* __restrict__ ebuf, const int* __restrict__ batch,
                      const float* __restrict__ dinv, int2* __restrict__ ebuf2)
{
    int e = blockIdx.x * 256 + threadIdx.x;
    if (e < EE) {
        int src = ebuf[e];
        ebuf2[e] = make_int2(batch[src], __float_as_int(dinv[src]));
    }
}

// ---------- W pre-conversion: W[128][128] -> hi/lo f16 frags in exact MFMA B-frag order ----
// frag (nt,ks,kq,m) = W^T[nt*16+m][ks*32+kq*8 .. +8)  stored at index ((nt*4+ks)*4+kq)*16+m
__global__ __launch_bounds__(256) void wprep_k(const float* __restrict__ W,
                                               f16x8* __restrict__ whi_f,
                                               f16x8* __restrict__ wlo_f)
{
    int tid = blockIdx.x * 256 + threadIdx.x;   // 0..2047
    int m  = tid & 15;
    int kq = (tid >> 4) & 3;
    int ks = (tid >> 6) & 3;
    int nt = tid >> 8;
    int n  = nt * 16 + m;
    int k0 = ks * 32 + kq * 8;
    f16x8 h8, l8;
    #pragma unroll
    for (int u = 0; u < 8; u++) {
        float x = W[(size_t)(k0 + u) * 128 + n];
        f16 h = (f16)x;
        h8[u] = h;
        l8[u] = (f16)(x - (float)h);
    }
    whi_f[tid] = h8;
    wlo_f[tid] = l8;
}

// ---------- LDS-free MFMA GEMM: out = dinv .* (in @ W), fp16 out, split-precision ----------
// 782 blocks x 4 waves x 16 rows. B-frags loaded straight from the pre-permuted 32KB hi/lo
// tables (L1/L2-resident, lane*16B coalesced). t = hi@Whi + lo@Whi + hi@Wlo (~f32 accuracy).
// C/D: col=lane&15, row=(lane>>4)*4+reg (HW-verified).
__global__ __launch_bounds__(256) void gemm_mfma2_k(const float* __restrict__ in,
                                                    const f16x8* __restrict__ whi_f,
                                                    const f16x8* __restrict__ wlo_f,
                                                    const float* __restrict__ dinv,
                                                    __half* __restrict__ out,
                                                    int rows)
{
    int tid  = threadIdx.x;
    int lane = tid & 63;
    int wv   = tid >> 6;
    int rB   = blockIdx.x * 64 + wv * 16;
    int m    = lane & 15;
    int kq   = lane >> 4;                  // 0..3
    int r    = rB + m;
    int rr   = (r < rows) ? r : (rows - 1);

    // A-frags: k = ks*32 + kq*8 + [0..8)
    f16x8 ahi[4], alo[4];
    const float* rp = in + (size_t)rr * 128 + kq * 8;
    #pragma unroll
    for (int ks = 0; ks < 4; ks++) {
        float4 p0 = *(const float4*)(rp + ks * 32);
        float4 p1 = *(const float4*)(rp + ks * 32 + 4);
        float xs[8] = {p0.x, p0.y, p0.z, p0.w, p1.x, p1.y, p1.z, p1.w};
        #pragma unroll
        for (int u = 0; u < 8; u++) {
            f16 h = (f16)xs[u];
            ahi[ks][u] = h;
            alo[ks][u] = (f16)(xs[u] - (float)h);
        }
    }

    f32x4 acc[8];
    #pragma unroll
    for (int n = 0; n < 8; n++) acc[n] = (f32x4){0.f, 0.f, 0.f, 0.f};

    #pragma unroll
    for (int nt = 0; nt < 8; nt++) {
        #pragma unroll
        for (int ks = 0; ks < 4; ks++) {
            int idx = ((nt * 4 + ks) * 4 + kq) * 16 + m;
            f16x8 bh = whi_f[idx];
            f16x8 bl = wlo_f[idx];
            acc[nt] = __builtin_amdgcn_mfma_f32_16x16x32_f16(ahi[ks], bh, acc[nt], 0, 0, 0);
            acc[nt] = __builtin_amdgcn_mfma_f32_16x16x32_f16(alo[ks], bh, acc[nt], 0, 0, 0);
            acc[nt] = __builtin_amdgcn_mfma_f32_16x16x32_f16(ahi[ks], bl, acc[nt], 0, 0, 0);
        }
    }

    // epilogue: row = kq*4 + reg, col = nt*16 + m; scale by dinv[row], store f16
    int   orow[4];
    float dv[4];
    #pragma unroll
    for (int j = 0; j < 4; j++) {
        int gr = rB + kq * 4 + j;
        orow[j] = gr;
        dv[j]   = (gr < rows) ? dinv[gr] : 0.f;
    }
    #pragma unroll
    for (int nt = 0; nt < 8; nt++) {
        int c = nt * 16 + m;
        #pragma unroll
        for (int j = 0; j < 4; j++) {
            if (orow[j] < rows)
                out[(size_t)orow[j] * 128 + c] = __float2half(acc[nt][j] * dv[j]);
        }
    }
}

// ---------- aggregation, feature-split (factorized norm) ----------
// blocks [0,NN) do features 0..63; blocks [NN,2NN) do 64..127 (1-D grid => phase ordering;
// per-phase gather footprint 6.4MB -> better per-XCD L2 hit; one 128B line per edge gather)
__global__ __launch_bounds__(64) void aggh_k(const __half* __restrict__ t,
                                             const int* __restrict__ rowptr,
                                             const int* __restrict__ ebuf,
                                             const float* __restrict__ dinv,
                                             const float* __restrict__ bias,
                                             float* __restrict__ out,
                                             int relu)
{
    int bid = blockIdx.x;
    int i = bid, h = 0;
    if (i >= NN) { i -= NN; h = 1; }
    int f = (h << 6) | threadIdx.x;          // feature 0..127
    float a = __half2float(t[(size_t)i * 128 + f]);   // self term (pre-scaled row)
    int e0 = __builtin_amdgcn_readfirstlane(rowptr[i]);
    int e1 = __builtin_amdgcn_readfirstlane(rowptr[i + 1]);
    int e = e0;
    for (; e + 7 < e1; e += 8) {
        int s0 = ebuf[e],     s1 = ebuf[e + 1];
        int s2 = ebuf[e + 2], s3 = ebuf[e + 3];
        int s4 = ebuf[e + 4], s5 = ebuf[e + 5];
        int s6 = ebuf[e + 6], s7 = ebuf[e + 7];
        float w0 = __half2float(t[(size_t)s0 * 128 + f]);
        float w1 = __half2float(t[(size_t)s1 * 128 + f]);
        float w2 = __half2float(t[(size_t)s2 * 128 + f]);
        float w3 = __half2float(t[(size_t)s3 * 128 + f]);
        float w4 = __half2float(t[(size_t)s4 * 128 + f]);
        float w5 = __half2float(t[(size_t)s5 * 128 + f]);
        float w6 = __half2float(t[(size_t)s6 * 128 + f]);
        float w7 = __half2float(t[(size_t)s7 * 128 + f]);
        a += w0 + w1 + w2 + w3 + w4 + w5 + w6 + w7;
    }
    for (; e < e1; e++) {
        a += __half2float(t[(size_t)ebuf[e] * 128 + f]);
    }
    float di = dinv[i];
    a = di * a + bias[f];
    if (relu) a = fmaxf(a, 0.f);
    out[(size_t)i * 128 + f] = a;
}

// conv3 aggregation: ebuf2 = {bg, w=dinv[src]}; zz L2-resident
__global__ __launch_bounds__(64) void agg_out_k(const float* __restrict__ zz,
                                                const int* __restrict__ batch,
                                                const int* __restrict__ rowptr,
                                                const int2* __restrict__ ebuf2,
                                                const float* __restrict__ dinv,
                                                const float* __restrict__ bias,
                                                float* __restrict__ out)
{
    int i = blockIdx.x;
    int f = threadIdx.x;
    const float2* zp = (const float2*)zz;
    float di = dinv[i];
    float2 v = zp[(size_t)batch[i] * 64 + f];
    float a0 = di * v.x, a1 = di * v.y;
    int e0 = rowptr[i], e1 = rowptr[i + 1];
    int e = e0;
    for (; e + 3 < e1; e += 4) {
        int2 r0 = ebuf2[e],     r1 = ebuf2[e + 1];
        int2 r2 = ebuf2[e + 2], r3 = ebuf2[e + 3];
        float2 w0 = zp[(size_t)r0.x * 64 + f];
        float2 w1 = zp[(size_t)r1.x * 64 + f];
        float2 w2 = zp[(size_t)r2.x * 64 + f];
        float2 w3 = zp[(size_t)r3.x * 64 + f];
        float n0 = __int_as_float(r0.y), n1 = __int_as_float(r1.y);
        float n2 = __int_as_float(r2.y), n3 = __int_as_float(r3.y);
        a0 += n0 * w0.x; a1 += n0 * w0.y;
        a0 += n1 * w1.x; a1 += n1 * w1.y;
        a0 += n2 * w2.x; a1 += n2 * w2.y;
        a0 += n3 * w3.x; a1 += n3 * w3.y;
    }
    for (; e < e1; e++) {
        int2 r = ebuf2[e];
        float nm = __int_as_float(r.y);
        float2 w = zp[(size_t)r.x * 64 + f];
        a0 += nm * w.x; a1 += nm * w.y;
    }
    float2 b = ((const float2*)bias)[f];
    a0 = di * a0 + b.x;
    a1 = di * a1 + b.y;
    ((float2*)out)[(size_t)i * 64 + f] = make_float2(a0, a1);
}

// ---------- pooling ----------
__global__ __launch_bounds__(128) void pool2_k(const float* __restrict__ h2,
                                               const int* __restrict__ batch,
                                               float* __restrict__ pooled)
{
    int g = blockIdx.x;
    int c = blockIdx.y;
    int f = threadIdx.x;
    int bs = lowerb(batch, NN, g);
    int be = lowerb(batch, NN, g + 1);
    int len = be - bs;
    int cs = bs + (int)(((long long)len * c) / PCH);
    int ce = bs + (int)(((long long)len * (c + 1)) / PCH);
    float a = 0.f;
    for (int i = cs; i < ce; i++) a += h2[(size_t)i * 128 + f];
    if (ce > cs) atomicAdd(&pooled[(size_t)g * 128 + f], a);
}

// ---------- fc ----------
__global__ __launch_bounds__(64) void fc_k(const float* __restrict__ pooled,
                                           const float* __restrict__ fcW,    // [128][64]
                                           const float* __restrict__ fcb,
                                           float* __restrict__ latentf,
                                           float* __restrict__ lat_out)
{
    int g = blockIdx.x, l = threadIdx.x;
    const float* p = pooled + (size_t)g * 128;
    float a = fcb[l];
    #pragma unroll 8
    for (int k = 0; k < 128; k++) a = fmaf(p[k], fcW[(size_t)k * 64 + l], a);
    a = fmaxf(a, 0.f);
    latentf[(size_t)g * 64 + l] = a;
    lat_out[(size_t)g * 64 + l] = a;
}

// ---------- decoder + W3 transform ----------
__global__ __launch_bounds__(128) void dec_k(const float* __restrict__ latentf,
                                             const float* __restrict__ decW,  // [64][128]
                                             const float* __restrict__ decb,
                                             const float* __restrict__ W3,    // [128][128]
                                             float* __restrict__ zz)
{
    __shared__ float zs[128];
    int g = blockIdx.x, c = threadIdx.x;
    const float* lat = latentf + (size_t)g * 64;
    {
        float a = decb[c];
        #pragma unroll 8
        for (int k = 0; k < 64; k++) a = fmaf(lat[k], decW[(size_t)k * 128 + c], a);
        zs[c] = fmaxf(a, 0.f);
    }
    __syncthreads();
    float o = 0.f;
    #pragma unroll 8
    for (int k = 0; k < 128; k++) o = fmaf(zs[k], W3[(size_t)k * 128 + c], o);
    zz[(size_t)g * 128 + c] = o;
}

extern "C" void kernel_launch(void* const* d_in, const int* in_sizes, int n_in,
                              void* d_out, int out_size, void* d_ws, size_t ws_size,
                              hipStream_t stream)
{
    const float* x     = (const float*)d_in[0];
    const int*   ei    = (const int*)d_in[1];
    const int*   batch = (const int*)d_in[2];
    const float* W1  = (const float*)d_in[3];
    const float* b1  = (const float*)d_in[4];
    const float* W2  = (const float*)d_in[5];
    const float* b2  = (const float*)d_in[6];
    const float* fcW = (const float*)d_in[7];
    const float* fcb = (const float*)d_in[8];
    const float* decW= (const float*)d_in[9];
    const float* decb= (const float*)d_in[10];
    const float* W3  = (const float*)d_in[11];
    const float* b3  = (const float*)d_in[12];

    char* ws = (char*)d_ws;
    size_t off = 0;
    auto alloc = [&](size_t bytes) -> char* {
        char* p = ws + off;
        off = (off + bytes + 255) & ~(size_t)255;
        return p;
    };
    float* dinv     = (float*)alloc((size_t)NN * 4);
    int*   rowptr   = (int*)alloc((size_t)(NN + 1) * 4);
    int*   bcur     = (int*)alloc((size_t)NB * 4);
    int*   bbase    = (int*)alloc((size_t)NB * 4);
    int*   ebuf     = (int*)alloc((size_t)EE * 4);           // CSR src indices (4B/edge)
    float* pooled   = (float*)alloc((size_t)GG * 128 * 4);
    float* latentf  = (float*)alloc((size_t)GG * 64 * 4);
    float* zz       = (float*)alloc((size_t)GG * 128 * 4);
    f16x8* whi1     = (f16x8*)alloc(2048 * 16);              // W1 hi frags (32KB)
    f16x8* wlo1     = (f16x8*)alloc(2048 * 16);
    f16x8* whi2     = (f16x8*)alloc(2048 * 16);
    f16x8* wlo2     = (f16x8*)alloc(2048 * 16);
    __half* A       = (__half*)alloc((size_t)NN * 128 * 2);  // pre-scaled transformed feats (fp16)
    float* B        = (float*)alloc((size_t)NN * 128 * 4);   // hidden activations h (f32)
    // aliases: eraw (NB*CAP*8 = 12.8MB) in B (25.6MB, consumed before aggh1 writes B);
    // ebuf2 (6.4MB) in A (12.8MB, built after aggh2 has consumed A)
    int2*  eraw     = (int2*)B;
    int2*  ebuf2    = (int2*)A;

    float* recon_out = (float*)d_out;
    float* lat_out   = (float*)d_out + (size_t)NN * 128;

    hipMemsetAsync(pooled, 0, (size_t)GG * 128 * 4, stream);
    init_k<<<(NB + 255) / 256, 256, 0, stream>>>(bcur);
    binA_k<<<ABLK, 512, 0, stream>>>(ei, bcur, eraw);
    scanb2_k<<<1, 512, 0, stream>>>(bcur, bbase, rowptr);
    binB_k<<<NB, 512, 0, stream>>>(eraw, bcur, bbase, rowptr, ebuf);
    dinv_k<<<(NN + 255) / 256, 256, 0, stream>>>(rowptr, dinv);
    wprep_k<<<8, 256, 0, stream>>>(W1, whi1, wlo1);
    wprep_k<<<8, 256, 0, stream>>>(W2, whi2, wlo2);

    int gblk = (NN + 63) / 64;   // 782
    // conv1: A = dinv .* (x @ W1) (fp16) ; h1 = relu(dinv.*(agg(A)) + b1) -> B
    gemm_mfma2_k<<<gblk, 256, 0, stream>>>(x, whi1, wlo1, dinv, A, NN);
    aggh_k<<<2 * NN, 64, 0, stream>>>(A, rowptr, ebuf, dinv, b1, B, 1);
    // conv2
    gemm_mfma2_k<<<gblk, 256, 0, stream>>>(B, whi2, wlo2, dinv, A, NN);
    aggh_k<<<2 * NN, 64, 0, stream>>>(A, rowptr, ebuf, dinv, b2, B, 1);
    // A free -> build ebuf2 {batch[src], dinv[src]}
    pbb_k<<<(EE + 255) / 256, 256, 0, stream>>>(ebuf, batch, dinv, ebuf2);
    // pool + fc (latent out) + decoder(+W3 transform)
    pool2_k<<<dim3(GG, PCH), 128, 0, stream>>>(B, batch, pooled);
    fc_k<<<GG, 64, 0, stream>>>(pooled, fcW, fcb, latentf, lat_out);
    dec_k<<<GG, 128, 0, stream>>>(latentf, decW, decb, W3, zz);
    // conv3 -> recon
    agg_out_k<<<NN, 64, 0, stream>>>(zz, batch, rowptr, ebuf2, dinv,
                                     b3, recon_out);
}

// Round 7
// 302.003 us; speedup vs baseline: 1.0632x; 1.0632x over previous
//
#include <hip/hip_runtime.h>
#include <hip/hip_fp16.h>

// Problem constants
static constexpr int NN   = 50000;
static constexpr int EE   = 800000;
static constexpr int GG   = 256;
static constexpr int PCH  = 16;                 // pooling chunks per graph
static constexpr int BK   = 128;                // targets per bucket
static constexpr int NB   = (NN + BK - 1) / BK; // 391 buckets (bucket = dst>>7)
static constexpr int CAP  = 4096;               // bucket region capacity (mean 2048, sigma 45)
static constexpr int CH   = 2048;               // edges per binA block
static constexpr int ABLK = (EE + CH - 1) / CH; // 391

typedef _Float16 f16;
typedef f16  f16x8 __attribute__((ext_vector_type(8)));
typedef float f32x4 __attribute__((ext_vector_type(4)));

// ---------- helpers ----------
__device__ __forceinline__ int lowerb(const int* __restrict__ b, int n, int v) {
    int lo = 0, hi = n;
    while (lo < hi) { int m = (lo + hi) >> 1; if (b[m] < v) lo = m + 1; else hi = m; }
    return lo;
}

// ---------- CSR build ----------
__global__ void init_k(int* __restrict__ bcur)
{
    int b = blockIdx.x * 256 + threadIdx.x;
    if (b < NB) bcur[b] = b * CAP;
}

// Pass A: partition edges into fixed-capacity bucket regions, coalesced flush.
__global__ __launch_bounds__(512) void binA_k(const int* __restrict__ ei,
                                              int* __restrict__ bcur,
                                              int2* __restrict__ eraw)
{
    __shared__ int2  stage[CH];
    __shared__ short sbid[CH];
    __shared__ int   hist[NB], loff[NB], gbase[NB], lcur[NB];
    __shared__ int   sc[512];

    int tid = threadIdx.x;
    int e0 = blockIdx.x * CH;
    int n = EE - e0; if (n > CH) n = CH;

    for (int b = tid; b < NB; b += 512) hist[b] = 0;
    __syncthreads();

    int2 r[CH / 512];
    #pragma unroll
    for (int k = 0; k < CH / 512; k++) {
        int s = k * 512 + tid;
        if (s < n) {
            int src = ei[e0 + s];
            int dst = ei[EE + e0 + s];
            r[k] = make_int2(src, dst);
            atomicAdd(&hist[dst >> 7], 1);
        }
    }
    __syncthreads();
    int v = (tid < NB) ? hist[tid] : 0;
    sc[tid] = v;
    __syncthreads();
    #pragma unroll
    for (int off = 1; off < 512; off <<= 1) {
        int add = (tid >= off) ? sc[tid - off] : 0;
        __syncthreads();
        sc[tid] += add;
        __syncthreads();
    }
    if (tid < NB) { int ex = sc[tid] - v; loff[tid] = ex; lcur[tid] = ex; }
    __syncthreads();
    for (int b = tid; b < NB; b += 512)
        gbase[b] = atomicAdd(&bcur[b], hist[b]);
    __syncthreads();
    #pragma unroll
    for (int k = 0; k < CH / 512; k++) {
        int s = k * 512 + tid;
        if (s < n) {
            int b = r[k].y >> 7;
            int slot = atomicAdd(&lcur[b], 1);
            stage[slot] = r[k];
            sbid[slot]  = (short)b;
        }
    }
    __syncthreads();
    for (int s = tid; s < n; s += 512) {
        int b = sbid[s];
        eraw[(size_t)gbase[b] + (s - loff[b])] = stage[s];
    }
}

// scan bucket totals -> bucket base offsets; rowptr[NN]=EE
__global__ __launch_bounds__(512) void scanb2_k(const int* __restrict__ bcur,
                                                int* __restrict__ bbase,
                                                int* __restrict__ rowptr)
{
    __shared__ int s[512];
    int t = threadIdx.x;
    int v = (t < NB) ? (bcur[t] - t * CAP) : 0;
    s[t] = v;
    __syncthreads();
    #pragma unroll
    for (int off = 1; off < 512; off <<= 1) {
        int add = (t >= off) ? s[t - off] : 0;
        __syncthreads();
        s[t] += add;
        __syncthreads();
    }
    if (t < NB) bbase[t] = s[t] - v;
    if (t == 0) rowptr[NN] = EE;
}

// Pass B: per bucket: LDS hist -> rowptr, place src ints at exact CSR slots
__global__ __launch_bounds__(512) void binB_k(const int2* __restrict__ eraw,
                                              const int* __restrict__ bcur,
                                              const int* __restrict__ bbase,
                                              int* __restrict__ rowptr,
                                              int* __restrict__ ebuf)
{
    __shared__ int hist[BK], excl[BK], cur[BK];
    int b = blockIdx.x, tid = threadIdx.x;
    int t0 = b << 7;
    int lim = NN - t0; if (lim > BK) lim = BK;
    int tot  = bcur[b] - b * CAP;
    int base = bbase[b];
    const int2* er = eraw + (size_t)b * CAP;

    if (tid < BK) hist[tid] = 0;
    __syncthreads();
    for (int s = tid; s < tot; s += 512) atomicAdd(&hist[er[s].y & 127], 1);
    __syncthreads();
    if (tid < BK) excl[tid] = hist[tid];
    __syncthreads();
    #pragma unroll
    for (int off = 1; off < BK; off <<= 1) {
        int add = (tid >= off && tid < BK) ? excl[tid - off] : 0;
        __syncthreads();
        if (tid < BK) excl[tid] += add;
        __syncthreads();
    }
    if (tid < BK) {
        int ex = excl[tid] - hist[tid];
        cur[tid] = base + ex;
        if (tid < lim) rowptr[t0 + tid] = base + ex;
    }
    __syncthreads();
    for (int s = tid; s < tot; s += 512) {
        int2 rec = er[s];
        int p = atomicAdd(&cur[rec.y & 127], 1);
        ebuf[p] = rec.x;
    }
}

// dinv from rowptr degree (+1 self-loop)
__global__ void dinv_k(const int* __restrict__ rowptr, float* __restrict__ dinv)
{
    int i = blockIdx.x * 256 + threadIdx.x;
    if (i < NN) dinv[i] = rsqrtf((float)(rowptr[i + 1] - rowptr[i] + 1));
}

// edge-parallel: ebuf2[e] = {batch[src], dinv[src]}
__global__ void pbb_k(const int* __restrict__ ebuf, const int* __restrict__ batch,
                      const float* __restrict__ dinv, int2* __restrict__ ebuf2)
{
    int e = blockIdx.x * 256 + threadIdx.x;
    if (e < EE) {
        int src = ebuf[e];
        ebuf2[e] = make_int2(batch[src], __float_as_int(dinv[src]));
    }
}

// ---------- W pre-conversion: W[128][128] -> hi/lo f16 frags in exact MFMA B-frag order ----
__global__ __launch_bounds__(256) void wprep_k(const float* __restrict__ W,
                                               f16x8* __restrict__ whi_f,
                                               f16x8* __restrict__ wlo_f)
{
    int tid = blockIdx.x * 256 + threadIdx.x;   // 0..2047
    int m  = tid & 15;
    int kq = (tid >> 4) & 3;
    int ks = (tid >> 6) & 3;
    int nt = tid >> 8;
    int n  = nt * 16 + m;
    int k0 = ks * 32 + kq * 8;
    f16x8 h8, l8;
    #pragma unroll
    for (int u = 0; u < 8; u++) {
        float x = W[(size_t)(k0 + u) * 128 + n];
        f16 h = (f16)x;
        h8[u] = h;
        l8[u] = (f16)(x - (float)h);
    }
    whi_f[tid] = h8;
    wlo_f[tid] = l8;
}

// ---------- LDS-free MFMA GEMM: out = dinv .* (in @ W), fp16 out, split-precision ----------
__global__ __launch_bounds__(256) void gemm_mfma2_k(const float* __restrict__ in,
                                                    const f16x8* __restrict__ whi_f,
                                                    const f16x8* __restrict__ wlo_f,
                                                    const float* __restrict__ dinv,
                                                    __half* __restrict__ out,
                                                    int rows)
{
    int tid  = threadIdx.x;
    int lane = tid & 63;
    int wv   = tid >> 6;
    int rB   = blockIdx.x * 64 + wv * 16;
    int m    = lane & 15;
    int kq   = lane >> 4;                  // 0..3
    int r    = rB + m;
    int rr   = (r < rows) ? r : (rows - 1);

    // A-frags: k = ks*32 + kq*8 + [0..8)
    f16x8 ahi[4], alo[4];
    const float* rp = in + (size_t)rr * 128 + kq * 8;
    #pragma unroll
    for (int ks = 0; ks < 4; ks++) {
        float4 p0 = *(const float4*)(rp + ks * 32);
        float4 p1 = *(const float4*)(rp + ks * 32 + 4);
        float xs[8] = {p0.x, p0.y, p0.z, p0.w, p1.x, p1.y, p1.z, p1.w};
        #pragma unroll
        for (int u = 0; u < 8; u++) {
            f16 h = (f16)xs[u];
            ahi[ks][u] = h;
            alo[ks][u] = (f16)(xs[u] - (float)h);
        }
    }

    f32x4 acc[8];
    #pragma unroll
    for (int n = 0; n < 8; n++) acc[n] = (f32x4){0.f, 0.f, 0.f, 0.f};

    #pragma unroll
    for (int nt = 0; nt < 8; nt++) {
        #pragma unroll
        for (int ks = 0; ks < 4; ks++) {
            int idx = ((nt * 4 + ks) * 4 + kq) * 16 + m;
            f16x8 bh = whi_f[idx];
            f16x8 bl = wlo_f[idx];
            acc[nt] = __builtin_amdgcn_mfma_f32_16x16x32_f16(ahi[ks], bh, acc[nt], 0, 0, 0);
            acc[nt] = __builtin_amdgcn_mfma_f32_16x16x32_f16(alo[ks], bh, acc[nt], 0, 0, 0);
            acc[nt] = __builtin_amdgcn_mfma_f32_16x16x32_f16(ahi[ks], bl, acc[nt], 0, 0, 0);
        }
    }

    // epilogue: row = kq*4 + reg, col = nt*16 + m; scale by dinv[row], store f16
    int   orow[4];
    float dv[4];
    #pragma unroll
    for (int j = 0; j < 4; j++) {
        int gr = rB + kq * 4 + j;
        orow[j] = gr;
        dv[j]   = (gr < rows) ? dinv[gr] : 0.f;
    }
    #pragma unroll
    for (int nt = 0; nt < 8; nt++) {
        int c = nt * 16 + m;
        #pragma unroll
        for (int j = 0; j < 4; j++) {
            if (orow[j] < rows)
                out[(size_t)orow[j] * 128 + c] = __float2half(acc[nt][j] * dv[j]);
        }
    }
}

// ---------- aggregation, paired-edge gather (factorized norm) ----------
// One block = one node, 64 threads. Lanes 0-31 process even edge-chunks, lanes 32-63 odd
// chunks; each lane covers 4 features (8B fp16). One wave instruction gathers TWO full
// 256B rows. Combine halves with __shfl_xor(32) at the end.
__device__ __forceinline__ float4 gat4h(const __half* __restrict__ t, int s, int q)
{
    uint2 v = *(const uint2*)(t + ((size_t)s << 7) + q * 4);
    __half2 a = __builtin_bit_cast(__half2, v.x);
    __half2 b = __builtin_bit_cast(__half2, v.y);
    float2 fa = __half22float2(a), fb = __half22float2(b);
    return make_float4(fa.x, fa.y, fb.x, fb.y);
}

__global__ __launch_bounds__(64) void aggh_k(const __half* __restrict__ t,
                                             const int* __restrict__ rowptr,
                                             const int* __restrict__ ebuf,
                                             const float* __restrict__ dinv,
                                             const float* __restrict__ bias,
                                             float* __restrict__ out,
                                             int relu)
{
    int i    = blockIdx.x;
    int lane = threadIdx.x;
    int half = lane >> 5;
    int q    = lane & 31;                // feature quad: feats q*4..q*4+3

    float a0 = 0.f, a1 = 0.f, a2 = 0.f, a3 = 0.f;
    if (half == 0) {                     // self term (pre-scaled row) in even stream
        float4 v = gat4h(t, i, q);
        a0 = v.x; a1 = v.y; a2 = v.z; a3 = v.w;
    }

    int e0 = __builtin_amdgcn_readfirstlane(rowptr[i]);
    int e1 = __builtin_amdgcn_readfirstlane(rowptr[i + 1]);
    int deg = e1 - e0;
    int full = deg & ~7;                 // main loop covers 8 edges/iter (4 per half)
    int ee = e0 + full;
    for (int e = e0 + half * 4; e < ee; e += 8) {
        int s0 = ebuf[e],     s1 = ebuf[e + 1];
        int s2 = ebuf[e + 2], s3 = ebuf[e + 3];
        float4 w0 = gat4h(t, s0, q);
        float4 w1 = gat4h(t, s1, q);
        float4 w2 = gat4h(t, s2, q);
        float4 w3 = gat4h(t, s3, q);
        a0 += w0.x + w1.x + w2.x + w3.x;
        a1 += w0.y + w1.y + w2.y + w3.y;
        a2 += w0.z + w1.z + w2.z + w3.z;
        a3 += w0.w + w1.w + w2.w + w3.w;
    }
    for (int e = ee + half; e < e1; e += 2) {   // tail, parity split
        float4 w = gat4h(t, ebuf[e], q);
        a0 += w.x; a1 += w.y; a2 += w.z; a3 += w.w;
    }
    // fold the two halves (both end holding the total)
    a0 += __shfl_xor(a0, 32);
    a1 += __shfl_xor(a1, 32);
    a2 += __shfl_xor(a2, 32);
    a3 += __shfl_xor(a3, 32);

    if (half == 0) {
        float di = dinv[i];
        float4 b = *(const float4*)(bias + q * 4);
        float4 o;
        o.x = di * a0 + b.x;
        o.y = di * a1 + b.y;
        o.z = di * a2 + b.z;
        o.w = di * a3 + b.w;
        if (relu) {
            o.x = fmaxf(o.x, 0.f); o.y = fmaxf(o.y, 0.f);
            o.z = fmaxf(o.z, 0.f); o.w = fmaxf(o.w, 0.f);
        }
        *(float4*)(out + (size_t)i * 128 + q * 4) = o;
    }
}

// conv3 aggregation, paired-edge: ebuf2 = {bg, w=dinv[src]}; zz (131KB) L2-resident.
// Lane covers float4 of the 512B row; halves process alternate edge-chunks.
__global__ __launch_bounds__(64) void agg_out_k(const float* __restrict__ zz,
                                                const int* __restrict__ batch,
                                                const int* __restrict__ rowptr,
                                                const int2* __restrict__ ebuf2,
                                                const float* __restrict__ dinv,
                                                const float* __restrict__ bias,
                                                float* __restrict__ out)
{
    int i    = blockIdx.x;
    int lane = threadIdx.x;
    int half = lane >> 5;
    int q    = lane & 31;
    float di = dinv[i];

    float a0 = 0.f, a1 = 0.f, a2 = 0.f, a3 = 0.f;
    if (half == 0) {                     // self term: di * zz[batch[i]]
        float4 v = *(const float4*)(zz + ((size_t)batch[i] << 7) + q * 4);
        a0 = di * v.x; a1 = di * v.y; a2 = di * v.z; a3 = di * v.w;
    }

    int e0 = rowptr[i], e1 = rowptr[i + 1];
    int deg = e1 - e0;
    int full = deg & ~7;
    int ee = e0 + full;
    for (int e = e0 + half * 4; e < ee; e += 8) {
        int2 r0 = ebuf2[e],     r1 = ebuf2[e + 1];
        int2 r2 = ebuf2[e + 2], r3 = ebuf2[e + 3];
        float4 w0 = *(const float4*)(zz + ((size_t)r0.x << 7) + q * 4);
        float4 w1 = *(const float4*)(zz + ((size_t)r1.x << 7) + q * 4);
        float4 w2 = *(const float4*)(zz + ((size_t)r2.x << 7) + q * 4);
        float4 w3 = *(const float4*)(zz + ((size_t)r3.x << 7) + q * 4);
        float n0 = __int_as_float(r0.y), n1 = __int_as_float(r1.y);
        float n2 = __int_as_float(r2.y), n3 = __int_as_float(r3.y);
        a0 += n0 * w0.x + n1 * w1.x + n2 * w2.x + n3 * w3.x;
        a1 += n0 * w0.y + n1 * w1.y + n2 * w2.y + n3 * w3.y;
        a2 += n0 * w0.z + n1 * w1.z + n2 * w2.z + n3 * w3.z;
        a3 += n0 * w0.w + n1 * w1.w + n2 * w2.w + n3 * w3.w;
    }
    for (int e = ee + half; e < e1; e += 2) {
        int2 r = ebuf2[e];
        float nm = __int_as_float(r.y);
        float4 w = *(const float4*)(zz + ((size_t)r.x << 7) + q * 4);
        a0 += nm * w.x; a1 += nm * w.y; a2 += nm * w.z; a3 += nm * w.w;
    }
    a0 += __shfl_xor(a0, 32);
    a1 += __shfl_xor(a1, 32);
    a2 += __shfl_xor(a2, 32);
    a3 += __shfl_xor(a3, 32);

    if (half == 0) {
        float4 b = *(const float4*)(bias + q * 4);
        float4 o;
        o.x = di * a0 + b.x;
        o.y = di * a1 + b.y;
        o.z = di * a2 + b.z;
        o.w = di * a3 + b.w;
        *(float4*)(out + (size_t)i * 128 + q * 4) = o;
    }
}

// ---------- pooling ----------
__global__ __launch_bounds__(128) void pool2_k(const float* __restrict__ h2,
                                               const int* __restrict__ batch,
                                               float* __restrict__ pooled)
{
    int g = blockIdx.x;
    int c = blockIdx.y;
    int f = threadIdx.x;
    int bs = lowerb(batch, NN, g);
    int be = lowerb(batch, NN, g + 1);
    int len = be - bs;
    int cs = bs + (int)(((long long)len * c) / PCH);
    int ce = bs + (int)(((long long)len * (c + 1)) / PCH);
    float a = 0.f;
    for (int i = cs; i < ce; i++) a += h2[(size_t)i * 128 + f];
    if (ce > cs) atomicAdd(&pooled[(size_t)g * 128 + f], a);
}

// ---------- fc ----------
__global__ __launch_bounds__(64) void fc_k(const float* __restrict__ pooled,
                                           const float* __restrict__ fcW,    // [128][64]
                                           const float* __restrict__ fcb,
                                           float* __restrict__ latentf,
                                           float* __restrict__ lat_out)
{
    int g = blockIdx.x, l = threadIdx.x;
    const float* p = pooled + (size_t)g * 128;
    float a = fcb[l];
    #pragma unroll 8
    for (int k = 0; k < 128; k++) a = fmaf(p[k], fcW[(size_t)k * 64 + l], a);
    a = fmaxf(a, 0.f);
    latentf[(size_t)g * 64 + l] = a;
    lat_out[(size_t)g * 64 + l] = a;
}

// ---------- decoder + W3 transform ----------
__global__ __launch_bounds__(128) void dec_k(const float* __restrict__ latentf,
                                             const float* __restrict__ decW,  // [64][128]
                                             const float* __restrict__ decb,
                                             const float* __restrict__ W3,    // [128][128]
                                             float* __restrict__ zz)
{
    __shared__ float zs[128];
    int g = blockIdx.x, c = threadIdx.x;
    const float* lat = latentf + (size_t)g * 64;
    {
        float a = decb[c];
        #pragma unroll 8
        for (int k = 0; k < 64; k++) a = fmaf(lat[k], decW[(size_t)k * 128 + c], a);
        zs[c] = fmaxf(a, 0.f);
    }
    __syncthreads();
    float o = 0.f;
    #pragma unroll 8
    for (int k = 0; k < 128; k++) o = fmaf(zs[k], W3[(size_t)k * 128 + c], o);
    zz[(size_t)g * 128 + c] = o;
}

extern "C" void kernel_launch(void* const* d_in, const int* in_sizes, int n_in,
                              void* d_out, int out_size, void* d_ws, size_t ws_size,
                              hipStream_t stream)
{
    const float* x     = (const float*)d_in[0];
    const int*   ei    = (const int*)d_in[1];
    const int*   batch = (const int*)d_in[2];
    const float* W1  = (const float*)d_in[3];
    const float* b1  = (const float*)d_in[4];
    const float* W2  = (const float*)d_in[5];
    const float* b2  = (const float*)d_in[6];
    const float* fcW = (const float*)d_in[7];
    const float* fcb = (const float*)d_in[8];
    const float* decW= (const float*)d_in[9];
    const float* decb= (const float*)d_in[10];
    const float* W3  = (const float*)d_in[11];
    const float* b3  = (const float*)d_in[12];

    char* ws = (char*)d_ws;
    size_t off = 0;
    auto alloc = [&](size_t bytes) -> char* {
        char* p = ws + off;
        off = (off + bytes + 255) & ~(size_t)255;
        return p;
    };
    float* dinv     = (float*)alloc((size_t)NN * 4);
    int*   rowptr   = (int*)alloc((size_t)(NN + 1) * 4);
    int*   bcur     = (int*)alloc((size_t)NB * 4);
    int*   bbase    = (int*)alloc((size_t)NB * 4);
    int*   ebuf     = (int*)alloc((size_t)EE * 4);           // CSR src indices (4B/edge)
    float* pooled   = (float*)alloc((size_t)GG * 128 * 4);
    float* latentf  = (float*)alloc((size_t)GG * 64 * 4);
    float* zz       = (float*)alloc((size_t)GG * 128 * 4);
    f16x8* whi1     = (f16x8*)alloc(2048 * 16);              // W1 hi frags (32KB)
    f16x8* wlo1     = (f16x8*)alloc(2048 * 16);
    f16x8* whi2     = (f16x8*)alloc(2048 * 16);
    f16x8* wlo2     = (f16x8*)alloc(2048 * 16);
    __half* A       = (__half*)alloc((size_t)NN * 128 * 2);  // pre-scaled transformed feats (fp16)
    float* B        = (float*)alloc((size_t)NN * 128 * 4);   // hidden activations h (f32)
    // aliases: eraw (NB*CAP*8 = 12.8MB) in B (25.6MB, consumed before aggh1 writes B);
    // ebuf2 (6.4MB) in A (12.8MB, built after aggh2 has consumed A)
    int2*  eraw     = (int2*)B;
    int2*  ebuf2    = (int2*)A;

    float* recon_out = (float*)d_out;
    float* lat_out   = (float*)d_out + (size_t)NN * 128;

    hipMemsetAsync(pooled, 0, (size_t)GG * 128 * 4, stream);
    init_k<<<(NB + 255) / 256, 256, 0, stream>>>(bcur);
    binA_k<<<ABLK, 512, 0, stream>>>(ei, bcur, eraw);
    scanb2_k<<<1, 512, 0, stream>>>(bcur, bbase, rowptr);
    binB_k<<<NB, 512, 0, stream>>>(eraw, bcur, bbase, rowptr, ebuf);
    dinv_k<<<(NN + 255) / 256, 256, 0, stream>>>(rowptr, dinv);
    wprep_k<<<8, 256, 0, stream>>>(W1, whi1, wlo1);
    wprep_k<<<8, 256, 0, stream>>>(W2, whi2, wlo2);

    int gblk = (NN + 63) / 64;   // 782
    // conv1: A = dinv .* (x @ W1) (fp16) ; h1 = relu(dinv.*(agg(A)) + b1) -> B
    gemm_mfma2_k<<<gblk, 256, 0, stream>>>(x, whi1, wlo1, dinv, A, NN);
    aggh_k<<<NN, 64, 0, stream>>>(A, rowptr, ebuf, dinv, b1, B, 1);
    // conv2
    gemm_mfma2_k<<<gblk, 256, 0, stream>>>(B, whi2, wlo2, dinv, A, NN);
    aggh_k<<<NN, 64, 0, stream>>>(A, rowptr, ebuf, dinv, b2, B, 1);
    // A free -> build ebuf2 {batch[src], dinv[src]}
    pbb_k<<<(EE + 255) / 256, 256, 0, stream>>>(ebuf, batch, dinv, ebuf2);
    // pool + fc (latent out) + decoder(+W3 transform)
    pool2_k<<<dim3(GG, PCH), 128, 0, stream>>>(B, batch, pooled);
    fc_k<<<GG, 64, 0, stream>>>(pooled, fcW, fcb, latentf, lat_out);
    dec_k<<<GG, 128, 0, stream>>>(latentf, decW, decb, W3, zz);
    // conv3 -> recon
    agg_out_k<<<NN, 64, 0, stream>>>(zz, batch, rowptr, ebuf2, dinv,
                                     b3, recon_out);
}

// Round 8
// 288.831 us; speedup vs baseline: 1.1116x; 1.0456x over previous
//
#include <hip/hip_runtime.h>
#include <hip/hip_fp16.h>

// Problem constants
static constexpr int NN   = 50000;
static constexpr int EE   = 800000;
static constexpr int GG   = 256;
static constexpr int PCH  = 16;                 // pooling chunks per graph
static constexpr int BK   = 128;                // targets per bucket
static constexpr int NB   = (NN + BK - 1) / BK; // 391 buckets (bucket = dst>>7)
static constexpr int CAP  = 4096;               // bucket region capacity (mean 2048, sigma 45)
static constexpr int CH   = 2048;               // edges per binA block
static constexpr int ABLK = (EE + CH - 1) / CH; // 391

typedef _Float16 f16;
typedef f16  f16x8 __attribute__((ext_vector_type(8)));
typedef float f32x4 __attribute__((ext_vector_type(4)));

// ---------- helpers ----------
__device__ __forceinline__ int lowerb(const int* __restrict__ b, int n, int v) {
    int lo = 0, hi = n;
    while (lo < hi) { int m = (lo + hi) >> 1; if (b[m] < v) lo = m + 1; else hi = m; }
    return lo;
}

// ---------- CSR build ----------
__global__ void init_k(int* __restrict__ bcur)
{
    int b = blockIdx.x * 256 + threadIdx.x;
    if (b < NB) bcur[b] = b * CAP;
}

// Pass A: partition edges into fixed-capacity bucket regions, coalesced flush.
__global__ __launch_bounds__(512) void binA_k(const int* __restrict__ ei,
                                              int* __restrict__ bcur,
                                              int2* __restrict__ eraw)
{
    __shared__ int2  stage[CH];
    __shared__ short sbid[CH];
    __shared__ int   hist[NB], loff[NB], gbase[NB], lcur[NB];
    __shared__ int   sc[512];

    int tid = threadIdx.x;
    int e0 = blockIdx.x * CH;
    int n = EE - e0; if (n > CH) n = CH;

    for (int b = tid; b < NB; b += 512) hist[b] = 0;
    __syncthreads();

    int2 r[CH / 512];
    #pragma unroll
    for (int k = 0; k < CH / 512; k++) {
        int s = k * 512 + tid;
        if (s < n) {
            int src = ei[e0 + s];
            int dst = ei[EE + e0 + s];
            r[k] = make_int2(src, dst);
            atomicAdd(&hist[dst >> 7], 1);
        }
    }
    __syncthreads();
    int v = (tid < NB) ? hist[tid] : 0;
    sc[tid] = v;
    __syncthreads();
    #pragma unroll
    for (int off = 1; off < 512; off <<= 1) {
        int add = (tid >= off) ? sc[tid - off] : 0;
        __syncthreads();
        sc[tid] += add;
        __syncthreads();
    }
    if (tid < NB) { int ex = sc[tid] - v; loff[tid] = ex; lcur[tid] = ex; }
    __syncthreads();
    for (int b = tid; b < NB; b += 512)
        gbase[b] = atomicAdd(&bcur[b], hist[b]);
    __syncthreads();
    #pragma unroll
    for (int k = 0; k < CH / 512; k++) {
        int s = k * 512 + tid;
        if (s < n) {
            int b = r[k].y >> 7;
            int slot = atomicAdd(&lcur[b], 1);
            stage[slot] = r[k];
            sbid[slot]  = (short)b;
        }
    }
    __syncthreads();
    for (int s = tid; s < n; s += 512) {
        int b = sbid[s];
        eraw[(size_t)gbase[b] + (s - loff[b])] = stage[s];
    }
}

// scan bucket totals -> bucket base offsets; rowptr[NN]=EE
__global__ __launch_bounds__(512) void scanb2_k(const int* __restrict__ bcur,
                                                int* __restrict__ bbase,
                                                int* __restrict__ rowptr)
{
    __shared__ int s[512];
    int t = threadIdx.x;
    int v = (t < NB) ? (bcur[t] - t * CAP) : 0;
    s[t] = v;
    __syncthreads();
    #pragma unroll
    for (int off = 1; off < 512; off <<= 1) {
        int add = (t >= off) ? s[t - off] : 0;
        __syncthreads();
        s[t] += add;
        __syncthreads();
    }
    if (t < NB) bbase[t] = s[t] - v;
    if (t == 0) rowptr[NN] = EE;
}

// Pass B: per bucket: LDS hist -> rowptr + dinv, place src ints at exact CSR slots
__global__ __launch_bounds__(512) void binB_k(const int2* __restrict__ eraw,
                                              const int* __restrict__ bcur,
                                              const int* __restrict__ bbase,
                                              int* __restrict__ rowptr,
                                              float* __restrict__ dinv,
                                              int* __restrict__ ebuf)
{
    __shared__ int hist[BK], excl[BK], cur[BK];
    int b = blockIdx.x, tid = threadIdx.x;
    int t0 = b << 7;
    int lim = NN - t0; if (lim > BK) lim = BK;
    int tot  = bcur[b] - b * CAP;
    int base = bbase[b];
    const int2* er = eraw + (size_t)b * CAP;

    if (tid < BK) hist[tid] = 0;
    __syncthreads();
    for (int s = tid; s < tot; s += 512) atomicAdd(&hist[er[s].y & 127], 1);
    __syncthreads();
    if (tid < BK) excl[tid] = hist[tid];
    __syncthreads();
    #pragma unroll
    for (int off = 1; off < BK; off <<= 1) {
        int add = (tid >= off && tid < BK) ? excl[tid - off] : 0;
        __syncthreads();
        if (tid < BK) excl[tid] += add;
        __syncthreads();
    }
    if (tid < BK) {
        int ex = excl[tid] - hist[tid];
        cur[tid] = base + ex;
        if (tid < lim) {
            rowptr[t0 + tid] = base + ex;
            dinv[t0 + tid]   = rsqrtf((float)(hist[tid] + 1));   // deg + self-loop
        }
    }
    __syncthreads();
    for (int s = tid; s < tot; s += 512) {
        int2 rec = er[s];
        int p = atomicAdd(&cur[rec.y & 127], 1);
        ebuf[p] = rec.x;
    }
}

// edge-parallel: ebuf2[e] = {batch[src], dinv[src]}
__global__ void pbb_k(const int* __restrict__ ebuf, const int* __restrict__ batch,
                      const float* __restrict__ dinv, int2* __restrict__ ebuf2)
{
    int e = blockIdx.x * 256 + threadIdx.x;
    if (e < EE) {
        int src = ebuf[e];
        ebuf2[e] = make_int2(batch[src], __float_as_int(dinv[src]));
    }
}

// ---------- W pre-conversion (both weights, one launch) ----------
// frag (nt,ks,kq,m) = W^T[nt*16+m][ks*32+kq*8 .. +8)  at index ((nt*4+ks)*4+kq)*16+m
__global__ __launch_bounds__(256) void wprep2_k(const float* __restrict__ W1,
                                                const float* __restrict__ W2,
                                                f16x8* __restrict__ whi1, f16x8* __restrict__ wlo1,
                                                f16x8* __restrict__ whi2, f16x8* __restrict__ wlo2)
{
    int blk = blockIdx.x;
    const float* W = (blk < 8) ? W1 : W2;
    f16x8* wh = (blk < 8) ? whi1 : whi2;
    f16x8* wl = (blk < 8) ? wlo1 : wlo2;
    int tid = (blk & 7) * 256 + threadIdx.x;    // 0..2047
    int m  = tid & 15;
    int kq = (tid >> 4) & 3;
    int ks = (tid >> 6) & 3;
    int nt = tid >> 8;
    int n  = nt * 16 + m;
    int k0 = ks * 32 + kq * 8;
    f16x8 h8, l8;
    #pragma unroll
    for (int u = 0; u < 8; u++) {
        float x = W[(size_t)(k0 + u) * 128 + n];
        f16 h = (f16)x;
        h8[u] = h;
        l8[u] = (f16)(x - (float)h);
    }
    wh[tid] = h8;
    wl[tid] = l8;
}

// ---------- MFMA GEMM: out = dinv .* (in @ W), fp16 out, split-precision ----------
// hi table staged in 32KB LDS (4 blocks/CU -> 4 waves/SIMD); lo read from L2 (1 of 3 MFMAs).
// C/D: col=lane&15, row=(lane>>4)*4+reg (HW-verified).
__global__ __launch_bounds__(256) void gemm_mfma3_k(const float* __restrict__ in,
                                                    const f16x8* __restrict__ whi_f,
                                                    const f16x8* __restrict__ wlo_f,
                                                    const float* __restrict__ dinv,
                                                    __half* __restrict__ out,
                                                    int rows)
{
    __shared__ __align__(16) f16x8 sh[2048];    // 32KB: hi frags, same indexing as table
    int tid  = threadIdx.x;
    #pragma unroll
    for (int u = 0; u < 8; u++) sh[u * 256 + tid] = whi_f[u * 256 + tid];
    __syncthreads();

    int lane = tid & 63;
    int wv   = tid >> 6;
    int rB   = blockIdx.x * 64 + wv * 16;
    int m    = lane & 15;
    int kq   = lane >> 4;                  // 0..3
    int r    = rB + m;
    int rr   = (r < rows) ? r : (rows - 1);

    // A-frags: k = ks*32 + kq*8 + [0..8)
    f16x8 ahi[4], alo[4];
    const float* rp = in + (size_t)rr * 128 + kq * 8;
    #pragma unroll
    for (int ks = 0; ks < 4; ks++) {
        float4 p0 = *(const float4*)(rp + ks * 32);
        float4 p1 = *(const float4*)(rp + ks * 32 + 4);
        float xs[8] = {p0.x, p0.y, p0.z, p0.w, p1.x, p1.y, p1.z, p1.w};
        #pragma unroll
        for (int u = 0; u < 8; u++) {
            f16 h = (f16)xs[u];
            ahi[ks][u] = h;
            alo[ks][u] = (f16)(xs[u] - (float)h);
        }
    }

    f32x4 acc[8];
    #pragma unroll
    for (int n = 0; n < 8; n++) acc[n] = (f32x4){0.f, 0.f, 0.f, 0.f};

    #pragma unroll
    for (int nt = 0; nt < 8; nt++) {
        #pragma unroll
        for (int ks = 0; ks < 4; ks++) {
            int idx = ((nt * 4 + ks) * 4 + kq) * 16 + m;
            f16x8 bh = sh[idx];
            f16x8 bl = wlo_f[idx];
            acc[nt] = __builtin_amdgcn_mfma_f32_16x16x32_f16(ahi[ks], bh, acc[nt], 0, 0, 0);
            acc[nt] = __builtin_amdgcn_mfma_f32_16x16x32_f16(alo[ks], bh, acc[nt], 0, 0, 0);
            acc[nt] = __builtin_amdgcn_mfma_f32_16x16x32_f16(ahi[ks], bl, acc[nt], 0, 0, 0);
        }
    }

    // epilogue: row = kq*4 + reg, col = nt*16 + m; scale by dinv[row], store f16
    int   orow[4];
    float dv[4];
    #pragma unroll
    for (int j = 0; j < 4; j++) {
        int gr = rB + kq * 4 + j;
        orow[j] = gr;
        dv[j]   = (gr < rows) ? dinv[gr] : 0.f;
    }
    #pragma unroll
    for (int nt = 0; nt < 8; nt++) {
        int c = nt * 16 + m;
        #pragma unroll
        for (int j = 0; j < 4; j++) {
            if (orow[j] < rows)
                out[(size_t)orow[j] * 128 + c] = __float2half(acc[nt][j] * dv[j]);
        }
    }
}

// ---------- aggregation: bulk-index + shfl, deep gather pipeline ----------
// One block = one node, 64 threads. Indices for up to 64 edges loaded in ONE instruction
// (lane l <- ebuf[e0+l]) then distributed via __shfl (VALU, off the memory chain).
// Main loop: 16 edges/iter, 8 gathers in flight per 32-lane half. Lane covers 4 features.
__device__ __forceinline__ float4 gat4h(const __half* __restrict__ t, int s, int q)
{
    uint2 v = *(const uint2*)(t + ((size_t)s << 7) + q * 4);
    __half2 a = __builtin_bit_cast(__half2, v.x);
    __half2 b = __builtin_bit_cast(__half2, v.y);
    float2 fa = __half22float2(a), fb = __half22float2(b);
    return make_float4(fa.x, fa.y, fb.x, fb.y);
}

__global__ __launch_bounds__(64) void aggh_k(const __half* __restrict__ t,
                                             const int* __restrict__ rowptr,
                                             const int* __restrict__ ebuf,
                                             const float* __restrict__ dinv,
                                             const float* __restrict__ bias,
                                             float* __restrict__ out,
                                             int relu)
{
    int i    = blockIdx.x;
    int lane = threadIdx.x;
    int half = lane >> 5;
    int q    = lane & 31;                // feature quad: feats q*4..q*4+3

    int e0 = __builtin_amdgcn_readfirstlane(rowptr[i]);
    int e1 = __builtin_amdgcn_readfirstlane(rowptr[i + 1]);
    int deg = e1 - e0;
    int idxsafe = (deg > 0) ? (e0 + min(lane, deg - 1)) : 0;
    int myidx = ebuf[idxsafe];           // bulk index load: one instr for <=64 edges

    float a0 = 0.f, a1 = 0.f, a2 = 0.f, a3 = 0.f;
    if (half == 0) {                     // self term (pre-scaled row)
        float4 v = gat4h(t, i, q);
        a0 = v.x; a1 = v.y; a2 = v.z; a3 = v.w;
    }

    int v   = min(deg, 64);
    int c16 = v & ~15;
    for (int j = half * 8; j < c16; j += 16) {   // 16 edges/iter, 8 gathers in flight/half
        int s0 = __shfl(myidx, j + 0), s1 = __shfl(myidx, j + 1);
        int s2 = __shfl(myidx, j + 2), s3 = __shfl(myidx, j + 3);
        int s4 = __shfl(myidx, j + 4), s5 = __shfl(myidx, j + 5);
        int s6 = __shfl(myidx, j + 6), s7 = __shfl(myidx, j + 7);
        float4 w0 = gat4h(t, s0, q);
        float4 w1 = gat4h(t, s1, q);
        float4 w2 = gat4h(t, s2, q);
        float4 w3 = gat4h(t, s3, q);
        float4 w4 = gat4h(t, s4, q);
        float4 w5 = gat4h(t, s5, q);
        float4 w6 = gat4h(t, s6, q);
        float4 w7 = gat4h(t, s7, q);
        a0 += w0.x + w1.x + w2.x + w3.x + w4.x + w5.x + w6.x + w7.x;
        a1 += w0.y + w1.y + w2.y + w3.y + w4.y + w5.y + w6.y + w7.y;
        a2 += w0.z + w1.z + w2.z + w3.z + w4.z + w5.z + w6.z + w7.z;
        a3 += w0.w + w1.w + w2.w + w3.w + w4.w + w5.w + w6.w + w7.w;
    }
    if (v - c16 >= 8) {                  // one 8-edge group (4 gathers/half)
        int j = c16 + half * 4;
        int s0 = __shfl(myidx, j + 0), s1 = __shfl(myidx, j + 1);
        int s2 = __shfl(myidx, j + 2), s3 = __shfl(myidx, j + 3);
        float4 w0 = gat4h(t, s0, q);
        float4 w1 = gat4h(t, s1, q);
        float4 w2 = gat4h(t, s2, q);
        float4 w3 = gat4h(t, s3, q);
        a0 += w0.x + w1.x + w2.x + w3.x;
        a1 += w0.y + w1.y + w2.y + w3.y;
        a2 += w0.z + w1.z + w2.z + w3.z;
        a3 += w0.w + w1.w + w2.w + w3.w;
    }
    int done = c16 + ((v - c16) & 8);
    for (int j = done + half; j < v; j += 2) {   // tail, parity split
        int s = __shfl(myidx, j);
        float4 w = gat4h(t, s, q);
        a0 += w.x; a1 += w.y; a2 += w.z; a3 += w.w;
    }
    for (int e = e0 + 64 + half; e < e1; e += 2) {   // rare deg>64 overflow
        float4 w = gat4h(t, ebuf[e], q);
        a0 += w.x; a1 += w.y; a2 += w.z; a3 += w.w;
    }

    // fold the two halves
    a0 += __shfl_xor(a0, 32);
    a1 += __shfl_xor(a1, 32);
    a2 += __shfl_xor(a2, 32);
    a3 += __shfl_xor(a3, 32);

    if (half == 0) {
        float di = dinv[i];
        float4 b = *(const float4*)(bias + q * 4);
        float4 o;
        o.x = di * a0 + b.x;
        o.y = di * a1 + b.y;
        o.z = di * a2 + b.z;
        o.w = di * a3 + b.w;
        if (relu) {
            o.x = fmaxf(o.x, 0.f); o.y = fmaxf(o.y, 0.f);
            o.z = fmaxf(o.z, 0.f); o.w = fmaxf(o.w, 0.f);
        }
        *(float4*)(out + (size_t)i * 128 + q * 4) = o;
    }
}

// conv3 aggregation, paired-edge: ebuf2 = {bg, w=dinv[src]}; zz (131KB) L2-resident.
__global__ __launch_bounds__(64) void agg_out_k(const float* __restrict__ zz,
                                                const int* __restrict__ batch,
                                                const int* __restrict__ rowptr,
                                                const int2* __restrict__ ebuf2,
                                                const float* __restrict__ dinv,
                                                const float* __restrict__ bias,
                                                float* __restrict__ out)
{
    int i    = blockIdx.x;
    int lane = threadIdx.x;
    int half = lane >> 5;
    int q    = lane & 31;
    float di = dinv[i];

    float a0 = 0.f, a1 = 0.f, a2 = 0.f, a3 = 0.f;
    if (half == 0) {                     // self term: di * zz[batch[i]]
        float4 v = *(const float4*)(zz + ((size_t)batch[i] << 7) + q * 4);
        a0 = di * v.x; a1 = di * v.y; a2 = di * v.z; a3 = di * v.w;
    }

    int e0 = rowptr[i], e1 = rowptr[i + 1];
    int deg = e1 - e0;
    int full = deg & ~7;
    int ee = e0 + full;
    for (int e = e0 + half * 4; e < ee; e += 8) {
        int2 r0 = ebuf2[e],     r1 = ebuf2[e + 1];
        int2 r2 = ebuf2[e + 2], r3 = ebuf2[e + 3];
        float4 w0 = *(const float4*)(zz + ((size_t)r0.x << 7) + q * 4);
        float4 w1 = *(const float4*)(zz + ((size_t)r1.x << 7) + q * 4);
        float4 w2 = *(const float4*)(zz + ((size_t)r2.x << 7) + q * 4);
        float4 w3 = *(const float4*)(zz + ((size_t)r3.x << 7) + q * 4);
        float n0 = __int_as_float(r0.y), n1 = __int_as_float(r1.y);
        float n2 = __int_as_float(r2.y), n3 = __int_as_float(r3.y);
        a0 += n0 * w0.x + n1 * w1.x + n2 * w2.x + n3 * w3.x;
        a1 += n0 * w0.y + n1 * w1.y + n2 * w2.y + n3 * w3.y;
        a2 += n0 * w0.z + n1 * w1.z + n2 * w2.z + n3 * w3.z;
        a3 += n0 * w0.w + n1 * w1.w + n2 * w2.w + n3 * w3.w;
    }
    for (int e = ee + half; e < e1; e += 2) {
        int2 r = ebuf2[e];
        float nm = __int_as_float(r.y);
        float4 w = *(const float4*)(zz + ((size_t)r.x << 7) + q * 4);
        a0 += nm * w.x; a1 += nm * w.y; a2 += nm * w.z; a3 += nm * w.w;
    }
    a0 += __shfl_xor(a0, 32);
    a1 += __shfl_xor(a1, 32);
    a2 += __shfl_xor(a2, 32);
    a3 += __shfl_xor(a3, 32);

    if (half == 0) {
        float4 b = *(const float4*)(bias + q * 4);
        float4 o;
        o.x = di * a0 + b.x;
        o.y = di * a1 + b.y;
        o.z = di * a2 + b.z;
        o.w = di * a3 + b.w;
        *(float4*)(out + (size_t)i * 128 + q * 4) = o;
    }
}

// ---------- pooling ----------
__global__ __launch_bounds__(128) void pool2_k(const float* __restrict__ h2,
                                               const int* __restrict__ batch,
                                               float* __restrict__ pooled)
{
    int g = blockIdx.x;
    int c = blockIdx.y;
    int f = threadIdx.x;
    int bs = lowerb(batch, NN, g);
    int be = lowerb(batch, NN, g + 1);
    int len = be - bs;
    int cs = bs + (int)(((long long)len * c) / PCH);
    int ce = bs + (int)(((long long)len * (c + 1)) / PCH);
    float a = 0.f;
    for (int i = cs; i < ce; i++) a += h2[(size_t)i * 128 + f];
    if (ce > cs) atomicAdd(&pooled[(size_t)g * 128 + f], a);
}

// ---------- fused fc + decoder + W3 transform ----------
// phase 1 (threads 0..63): latent = relu(pooled@fcW+fcb) -> LDS + lat_out
// phase 2 (all 128):       zz = relu(latent@decW+decb) @ W3
__global__ __launch_bounds__(128) void fcdec_k(const float* __restrict__ pooled,
                                               const float* __restrict__ fcW,   // [128][64]
                                               const float* __restrict__ fcb,
                                               const float* __restrict__ decW,  // [64][128]
                                               const float* __restrict__ decb,
                                               const float* __restrict__ W3,    // [128][128]
                                               float* __restrict__ lat_out,
                                               float* __restrict__ zz)
{
    __shared__ float lat[64];
    __shared__ float zs[128];
    int g = blockIdx.x, c = threadIdx.x;
    if (c < 64) {
        const float* p = pooled + (size_t)g * 128;
        float a = fcb[c];
        #pragma unroll 8
        for (int k = 0; k < 128; k++) a = fmaf(p[k], fcW[(size_t)k * 64 + c], a);
        a = fmaxf(a, 0.f);
        lat[c] = a;
        lat_out[(size_t)g * 64 + c] = a;
    }
    __syncthreads();
    {
        float a = decb[c];
        #pragma unroll 8
        for (int k = 0; k < 64; k++) a = fmaf(lat[k], decW[(size_t)k * 128 + c], a);
        zs[c] = fmaxf(a, 0.f);
    }
    __syncthreads();
    float o = 0.f;
    #pragma unroll 8
    for (int k = 0; k < 128; k++) o = fmaf(zs[k], W3[(size_t)k * 128 + c], o);
    zz[(size_t)g * 128 + c] = o;
}

extern "C" void kernel_launch(void* const* d_in, const int* in_sizes, int n_in,
                              void* d_out, int out_size, void* d_ws, size_t ws_size,
                              hipStream_t stream)
{
    const float* x     = (const float*)d_in[0];
    const int*   ei    = (const int*)d_in[1];
    const int*   batch = (const int*)d_in[2];
    const float* W1  = (const float*)d_in[3];
    const float* b1  = (const float*)d_in[4];
    const float* W2  = (const float*)d_in[5];
    const float* b2  = (const float*)d_in[6];
    const float* fcW = (const float*)d_in[7];
    const float* fcb = (const float*)d_in[8];
    const float* decW= (const float*)d_in[9];
    const float* decb= (const float*)d_in[10];
    const float* W3  = (const float*)d_in[11];
    const float* b3  = (const float*)d_in[12];

    char* ws = (char*)d_ws;
    size_t off = 0;
    auto alloc = [&](size_t bytes) -> char* {
        char* p = ws + off;
        off = (off + bytes + 255) & ~(size_t)255;
        return p;
    };
    float* dinv     = (float*)alloc((size_t)NN * 4);
    int*   rowptr   = (int*)alloc((size_t)(NN + 1) * 4);
    int*   bcur     = (int*)alloc((size_t)NB * 4);
    int*   bbase    = (int*)alloc((size_t)NB * 4);
    int*   ebuf     = (int*)alloc((size_t)EE * 4);           // CSR src indices (4B/edge)
    int2*  ebuf2    = (int2*)alloc((size_t)EE * 8);          // {batch[src], dinv[src]}
    float* pooled   = (float*)alloc((size_t)GG * 128 * 4);
    float* zz       = (float*)alloc((size_t)GG * 128 * 4);
    f16x8* whi1     = (f16x8*)alloc(2048 * 16);              // W1 hi frags (32KB)
    f16x8* wlo1     = (f16x8*)alloc(2048 * 16);
    f16x8* whi2     = (f16x8*)alloc(2048 * 16);
    f16x8* wlo2     = (f16x8*)alloc(2048 * 16);
    __half* A       = (__half*)alloc((size_t)NN * 128 * 2);  // pre-scaled transformed feats (fp16)
    float* B        = (float*)alloc((size_t)NN * 128 * 4);   // hidden activations h (f32)
    // eraw (NB*CAP*8 = 12.8MB) aliases B (25.6MB): consumed by binB before aggh1 writes B
    int2*  eraw     = (int2*)B;

    float* recon_out = (float*)d_out;
    float* lat_out   = (float*)d_out + (size_t)NN * 128;

    hipMemsetAsync(pooled, 0, (size_t)GG * 128 * 4, stream);
    init_k<<<(NB + 255) / 256, 256, 0, stream>>>(bcur);
    binA_k<<<ABLK, 512, 0, stream>>>(ei, bcur, eraw);
    scanb2_k<<<1, 512, 0, stream>>>(bcur, bbase, rowptr);
    binB_k<<<NB, 512, 0, stream>>>(eraw, bcur, bbase, rowptr, dinv, ebuf);
    wprep2_k<<<16, 256, 0, stream>>>(W1, W2, whi1, wlo1, whi2, wlo2);
    pbb_k<<<(EE + 255) / 256, 256, 0, stream>>>(ebuf, batch, dinv, ebuf2);

    int gblk = (NN + 63) / 64;   // 782
    // conv1: A = dinv .* (x @ W1) (fp16) ; h1 = relu(dinv.*(agg(A)) + b1) -> B
    gemm_mfma3_k<<<gblk, 256, 0, stream>>>(x, whi1, wlo1, dinv, A, NN);
    aggh_k<<<NN, 64, 0, stream>>>(A, rowptr, ebuf, dinv, b1, B, 1);
    // conv2
    gemm_mfma3_k<<<gblk, 256, 0, stream>>>(B, whi2, wlo2, dinv, A, NN);
    aggh_k<<<NN, 64, 0, stream>>>(A, rowptr, ebuf, dinv, b2, B, 1);
    // pool + fused fc/dec (latent out) + conv3
    pool2_k<<<dim3(GG, PCH), 128, 0, stream>>>(B, batch, pooled);
    fcdec_k<<<GG, 128, 0, stream>>>(pooled, fcW, fcb, decW, decb, W3, lat_out, zz);
    agg_out_k<<<NN, 64, 0, stream>>>(zz, batch, rowptr, ebuf2, dinv,
                                     b3, recon_out);
}

// Round 10
// 286.061 us; speedup vs baseline: 1.1224x; 1.0097x over previous
//
#include <hip/hip_runtime.h>
#include <hip/hip_fp16.h>

// Problem constants
static constexpr int NN   = 50000;
static constexpr int EE   = 800000;
static constexpr int GG   = 256;
static constexpr int PCH  = 16;                 // pooling chunks per graph
static constexpr int BK   = 128;                // targets per bucket
static constexpr int NB   = (NN + BK - 1) / BK; // 391 buckets (bucket = dst>>7)
static constexpr int CAP  = 4096;               // bucket region capacity (mean 2048, sigma 45)
static constexpr int CH   = 2048;               // edges per binA block
static constexpr int ABLK = (EE + CH - 1) / CH; // 391

typedef _Float16 f16;
typedef f16  f16x8 __attribute__((ext_vector_type(8)));
typedef float f32x4 __attribute__((ext_vector_type(4)));

// ---------- helpers ----------
__device__ __forceinline__ int lowerb(const int* __restrict__ b, int n, int v) {
    int lo = 0, hi = n;
    while (lo < hi) { int m = (lo + hi) >> 1; if (b[m] < v) lo = m + 1; else hi = m; }
    return lo;
}

// ---------- fused prep: W1/W2 frag conversion + bcur init + pooled zeroing ----------
// frag (nt,ks,kq,m) = W^T[nt*16+m][ks*32+kq*8 .. +8)  at index ((nt*4+ks)*4+kq)*16+m
__global__ __launch_bounds__(256) void prep_k(const float* __restrict__ W1,
                                              const float* __restrict__ W2,
                                              f16x8* __restrict__ whi1, f16x8* __restrict__ wlo1,
                                              f16x8* __restrict__ whi2, f16x8* __restrict__ wlo2,
                                              int* __restrict__ bcur,
                                              float* __restrict__ pooled)
{
    int blk = blockIdx.x, t = threadIdx.x;
    if (blk < 16) {
        const float* W = (blk < 8) ? W1 : W2;
        f16x8* wh = (blk < 8) ? whi1 : whi2;
        f16x8* wl = (blk < 8) ? wlo1 : wlo2;
        int tid = (blk & 7) * 256 + t;      // 0..2047
        int m  = tid & 15;
        int kq = (tid >> 4) & 3;
        int ks = (tid >> 6) & 3;
        int nt = tid >> 8;
        int n  = nt * 16 + m;
        int k0 = ks * 32 + kq * 8;
        f16x8 h8, l8;
        #pragma unroll
        for (int u = 0; u < 8; u++) {
            float x = W[(size_t)(k0 + u) * 128 + n];
            f16 h = (f16)x;
            h8[u] = h;
            l8[u] = (f16)(x - (float)h);
        }
        wh[tid] = h8;
        wl[tid] = l8;
    } else if (blk == 16) {
        for (int b = t; b < NB; b += 256) bcur[b] = b * CAP;
    } else {
        float4* p = (float4*)pooled;        // GG*128 floats = 8192 float4
        for (int j = (blk - 17) * 256 + t; j < GG * 32; j += 512)
            p[j] = make_float4(0.f, 0.f, 0.f, 0.f);
    }
}

// Pass A: partition edges into fixed-capacity bucket regions, coalesced flush.
__global__ __launch_bounds__(512) void binA_k(const int* __restrict__ ei,
                                              int* __restrict__ bcur,
                                              int2* __restrict__ eraw)
{
    __shared__ int2  stage[CH];
    __shared__ short sbid[CH];
    __shared__ int   hist[NB], loff[NB], gbase[NB], lcur[NB];
    __shared__ int   sc[512];

    int tid = threadIdx.x;
    int e0 = blockIdx.x * CH;
    int n = EE - e0; if (n > CH) n = CH;

    for (int b = tid; b < NB; b += 512) hist[b] = 0;
    __syncthreads();

    int2 r[CH / 512];
    #pragma unroll
    for (int k = 0; k < CH / 512; k++) {
        int s = k * 512 + tid;
        if (s < n) {
            int src = ei[e0 + s];
            int dst = ei[EE + e0 + s];
            r[k] = make_int2(src, dst);
            atomicAdd(&hist[dst >> 7], 1);
        }
    }
    __syncthreads();
    int v = (tid < NB) ? hist[tid] : 0;
    sc[tid] = v;
    __syncthreads();
    #pragma unroll
    for (int off = 1; off < 512; off <<= 1) {
        int add = (tid >= off) ? sc[tid - off] : 0;
        __syncthreads();
        sc[tid] += add;
        __syncthreads();
    }
    if (tid < NB) { int ex = sc[tid] - v; loff[tid] = ex; lcur[tid] = ex; }
    __syncthreads();
    for (int b = tid; b < NB; b += 512)
        gbase[b] = atomicAdd(&bcur[b], hist[b]);
    __syncthreads();
    #pragma unroll
    for (int k = 0; k < CH / 512; k++) {
        int s = k * 512 + tid;
        if (s < n) {
            int b = r[k].y >> 7;
            int slot = atomicAdd(&lcur[b], 1);
            stage[slot] = r[k];
            sbid[slot]  = (short)b;
        }
    }
    __syncthreads();
    for (int s = tid; s < n; s += 512) {
        int b = sbid[s];
        eraw[(size_t)gbase[b] + (s - loff[b])] = stage[s];
    }
}

// scan bucket totals -> bucket base offsets; rowptr[NN]=EE
__global__ __launch_bounds__(512) void scanb2_k(const int* __restrict__ bcur,
                                                int* __restrict__ bbase,
                                                int* __restrict__ rowptr)
{
    __shared__ int s[512];
    int t = threadIdx.x;
    int v = (t < NB) ? (bcur[t] - t * CAP) : 0;
    s[t] = v;
    __syncthreads();
    #pragma unroll
    for (int off = 1; off < 512; off <<= 1) {
        int add = (t >= off) ? s[t - off] : 0;
        __syncthreads();
        s[t] += add;
        __syncthreads();
    }
    if (t < NB) bbase[t] = s[t] - v;
    if (t == 0) rowptr[NN] = EE;
}

// Pass B: per bucket: LDS hist -> rowptr + dinv, place src ints at exact CSR slots
__global__ __launch_bounds__(512) void binB_k(const int2* __restrict__ eraw,
                                              const int* __restrict__ bcur,
                                              const int* __restrict__ bbase,
                                              int* __restrict__ rowptr,
                                              float* __restrict__ dinv,
                                              int* __restrict__ ebuf)
{
    __shared__ int hist[BK], excl[BK], cur[BK];
    int b = blockIdx.x, tid = threadIdx.x;
    int t0 = b << 7;
    int lim = NN - t0; if (lim > BK) lim = BK;
    int tot  = bcur[b] - b * CAP;
    int base = bbase[b];
    const int2* er = eraw + (size_t)b * CAP;

    if (tid < BK) hist[tid] = 0;
    __syncthreads();
    for (int s = tid; s < tot; s += 512) atomicAdd(&hist[er[s].y & 127], 1);
    __syncthreads();
    if (tid < BK) excl[tid] = hist[tid];
    __syncthreads();
    #pragma unroll
    for (int off = 1; off < BK; off <<= 1) {
        int add = (tid >= off && tid < BK) ? excl[tid - off] : 0;
        __syncthreads();
        if (tid < BK) excl[tid] += add;
        __syncthreads();
    }
    if (tid < BK) {
        int ex = excl[tid] - hist[tid];
        cur[tid] = base + ex;
        if (tid < lim) {
            rowptr[t0 + tid] = base + ex;
            dinv[t0 + tid]   = rsqrtf((float)(hist[tid] + 1));   // deg + self-loop
        }
    }
    __syncthreads();
    for (int s = tid; s < tot; s += 512) {
        int2 rec = er[s];
        int p = atomicAdd(&cur[rec.y & 127], 1);
        ebuf[p] = rec.x;
    }
}

// edge-parallel: ebuf2[e] = {batch[src], dinv[src]}
__global__ void pbb_k(const int* __restrict__ ebuf, const int* __restrict__ batch,
                      const float* __restrict__ dinv, int2* __restrict__ ebuf2)
{
    int e = blockIdx.x * 256 + threadIdx.x;
    if (e < EE) {
        int src = ebuf[e];
        ebuf2[e] = make_int2(batch[src], __float_as_int(dinv[src]));
    }
}

// ---------- MFMA GEMM: out = dinv .* (in @ W), fp16 out, split-precision ----------
// hi table staged in 32KB LDS; lo read from L2 (1 of 3 MFMAs).
// C/D: col=lane&15, row=(lane>>4)*4+reg (HW-verified).
__global__ __launch_bounds__(256) void gemm_mfma3_k(const float* __restrict__ in,
                                                    const f16x8* __restrict__ whi_f,
                                                    const f16x8* __restrict__ wlo_f,
                                                    const float* __restrict__ dinv,
                                                    __half* __restrict__ out,
                                                    int rows)
{
    __shared__ __align__(16) f16x8 sh[2048];    // 32KB: hi frags, same indexing as table
    int tid  = threadIdx.x;
    #pragma unroll
    for (int u = 0; u < 8; u++) sh[u * 256 + tid] = whi_f[u * 256 + tid];
    __syncthreads();

    int lane = tid & 63;
    int wv   = tid >> 6;
    int rB   = blockIdx.x * 64 + wv * 16;
    int m    = lane & 15;
    int kq   = lane >> 4;                  // 0..3
    int r    = rB + m;
    int rr   = (r < rows) ? r : (rows - 1);

    // A-frags: k = ks*32 + kq*8 + [0..8)
    f16x8 ahi[4], alo[4];
    const float* rp = in + (size_t)rr * 128 + kq * 8;
    #pragma unroll
    for (int ks = 0; ks < 4; ks++) {
        float4 p0 = *(const float4*)(rp + ks * 32);
        float4 p1 = *(const float4*)(rp + ks * 32 + 4);
        float xs[8] = {p0.x, p0.y, p0.z, p0.w, p1.x, p1.y, p1.z, p1.w};
        #pragma unroll
        for (int u = 0; u < 8; u++) {
            f16 h = (f16)xs[u];
            ahi[ks][u] = h;
            alo[ks][u] = (f16)(xs[u] - (float)h);
        }
    }

    f32x4 acc[8];
    #pragma unroll
    for (int n = 0; n < 8; n++) acc[n] = (f32x4){0.f, 0.f, 0.f, 0.f};

    #pragma unroll
    for (int nt = 0; nt < 8; nt++) {
        #pragma unroll
        for (int ks = 0; ks < 4; ks++) {
            int idx = ((nt * 4 + ks) * 4 + kq) * 16 + m;
            f16x8 bh = sh[idx];
            f16x8 bl = wlo_f[idx];
            acc[nt] = __builtin_amdgcn_mfma_f32_16x16x32_f16(ahi[ks], bh, acc[nt], 0, 0, 0);
            acc[nt] = __builtin_amdgcn_mfma_f32_16x16x32_f16(alo[ks], bh, acc[nt], 0, 0, 0);
            acc[nt] = __builtin_amdgcn_mfma_f32_16x16x32_f16(ahi[ks], bl, acc[nt], 0, 0, 0);
        }
    }

    // epilogue: row = kq*4 + reg, col = nt*16 + m; scale by dinv[row], store f16
    int   orow[4];
    float dv[4];
    #pragma unroll
    for (int j = 0; j < 4; j++) {
        int gr = rB + kq * 4 + j;
        orow[j] = gr;
        dv[j]   = (gr < rows) ? dinv[gr] : 0.f;
    }
    #pragma unroll
    for (int nt = 0; nt < 8; nt++) {
        int c = nt * 16 + m;
        #pragma unroll
        for (int j = 0; j < 4; j++) {
            if (orow[j] < rows)
                out[(size_t)orow[j] * 128 + c] = __float2half(acc[nt][j] * dv[j]);
        }
    }
}

// ---------- aggregation: bulk-index + shfl, deep gather pipeline (PROVEN r8 version) ----
// One block = one node, 64 threads. Indices for up to 64 edges loaded in ONE instruction
// (lane l <- ebuf[e0+l]) then distributed via __shfl (VALU, off the memory chain).
// Main loop: 16 edges/iter, 8 gathers in flight per 32-lane half. Lane covers 4 features.
__device__ __forceinline__ float4 gat4h(const __half* __restrict__ t, int s, int q)
{
    uint2 v = *(const uint2*)(t + ((size_t)s << 7) + q * 4);
    __half2 a = __builtin_bit_cast(__half2, v.x);
    __half2 b = __builtin_bit_cast(__half2, v.y);
    float2 fa = __half22float2(a), fb = __half22float2(b);
    return make_float4(fa.x, fa.y, fb.x, fb.y);
}

__global__ __launch_bounds__(64) void aggh_k(const __half* __restrict__ t,
                                             const int* __restrict__ rowptr,
                                             const int* __restrict__ ebuf,
                                             const float* __restrict__ dinv,
                                             const float* __restrict__ bias,
                                             float* __restrict__ out,
                                             int relu)
{
    int i    = blockIdx.x;
    int lane = threadIdx.x;
    int half = lane >> 5;
    int q    = lane & 31;                // feature quad: feats q*4..q*4+3

    int e0 = __builtin_amdgcn_readfirstlane(rowptr[i]);
    int e1 = __builtin_amdgcn_readfirstlane(rowptr[i + 1]);
    int deg = e1 - e0;
    int idxsafe = (deg > 0) ? (e0 + min(lane, deg - 1)) : 0;
    int myidx = ebuf[idxsafe];           // bulk index load: one instr for <=64 edges

    float a0 = 0.f, a1 = 0.f, a2 = 0.f, a3 = 0.f;
    if (half == 0) {                     // self term (pre-scaled row)
        float4 v = gat4h(t, i, q);
        a0 = v.x; a1 = v.y; a2 = v.z; a3 = v.w;
    }

    int v   = min(deg, 64);
    int c16 = v & ~15;
    for (int j = half * 8; j < c16; j += 16) {   // 16 edges/iter, 8 gathers in flight/half
        int s0 = __shfl(myidx, j + 0), s1 = __shfl(myidx, j + 1);
        int s2 = __shfl(myidx, j + 2), s3 = __shfl(myidx, j + 3);
        int s4 = __shfl(myidx, j + 4), s5 = __shfl(myidx, j + 5);
        int s6 = __shfl(myidx, j + 6), s7 = __shfl(myidx, j + 7);
        float4 w0 = gat4h(t, s0, q);
        float4 w1 = gat4h(t, s1, q);
        float4 w2 = gat4h(t, s2, q);
        float4 w3 = gat4h(t, s3, q);
        float4 w4 = gat4h(t, s4, q);
        float4 w5 = gat4h(t, s5, q);
        float4 w6 = gat4h(t, s6, q);
        float4 w7 = gat4h(t, s7, q);
        a0 += w0.x + w1.x + w2.x + w3.x + w4.x + w5.x + w6.x + w7.x;
        a1 += w0.y + w1.y + w2.y + w3.y + w4.y + w5.y + w6.y + w7.y;
        a2 += w0.z + w1.z + w2.z + w3.z + w4.z + w5.z + w6.z + w7.z;
        a3 += w0.w + w1.w + w2.w + w3.w + w4.w + w5.w + w6.w + w7.w;
    }
    if (v - c16 >= 8) {                  // one 8-edge group (4 gathers/half)
        int j = c16 + half * 4;
        int s0 = __shfl(myidx, j + 0), s1 = __shfl(myidx, j + 1);
        int s2 = __shfl(myidx, j + 2), s3 = __shfl(myidx, j + 3);
        float4 w0 = gat4h(t, s0, q);
        float4 w1 = gat4h(t, s1, q);
        float4 w2 = gat4h(t, s2, q);
        float4 w3 = gat4h(t, s3, q);
        a0 += w0.x + w1.x + w2.x + w3.x;
        a1 += w0.y + w1.y + w2.y + w3.y;
        a2 += w0.z + w1.z + w2.z + w3.z;
        a3 += w0.w + w1.w + w2.w + w3.w;
    }
    int done = c16 + ((v - c16) & 8);
    for (int j = done + half; j < v; j += 2) {   // tail, parity split
        int s = __shfl(myidx, j);
        float4 w = gat4h(t, s, q);
        a0 += w.x; a1 += w.y; a2 += w.z; a3 += w.w;
    }
    for (int e = e0 + 64 + half; e < e1; e += 2) {   // rare deg>64 overflow
        float4 w = gat4h(t, ebuf[e], q);
        a0 += w.x; a1 += w.y; a2 += w.z; a3 += w.w;
    }

    // fold the two halves
    a0 += __shfl_xor(a0, 32);
    a1 += __shfl_xor(a1, 32);
    a2 += __shfl_xor(a2, 32);
    a3 += __shfl_xor(a3, 32);

    if (half == 0) {
        float di = dinv[i];
        float4 b = *(const float4*)(bias + q * 4);
        float4 o;
        o.x = di * a0 + b.x;
        o.y = di * a1 + b.y;
        o.z = di * a2 + b.z;
        o.w = di * a3 + b.w;
        if (relu) {
            o.x = fmaxf(o.x, 0.f); o.y = fmaxf(o.y, 0.f);
            o.z = fmaxf(o.z, 0.f); o.w = fmaxf(o.w, 0.f);
        }
        *(float4*)(out + (size_t)i * 128 + q * 4) = o;
    }
}

// conv3 aggregation, paired-edge (PROVEN r8 version): ebuf2 = {bg, w=dinv[src]};
// zz (131KB) L2-resident. Lane covers float4; halves process alternate edge-chunks.
__global__ __launch_bounds__(64) void agg_out_k(const float* __restrict__ zz,
                                                const int* __restrict__ batch,
                                                const int* __restrict__ rowptr,
                                                const int2* __restrict__ ebuf2,
                                                const float* __restrict__ dinv,
                                                const float* __restrict__ bias,
                                                float* __restrict__ out)
{
    int i    = blockIdx.x;
    int lane = threadIdx.x;
    int half = lane >> 5;
    int q    = lane & 31;
    float di = dinv[i];

    float a0 = 0.f, a1 = 0.f, a2 = 0.f, a3 = 0.f;
    if (half == 0) {                     // self term: di * zz[batch[i]]
        float4 v = *(const float4*)(zz + ((size_t)batch[i] << 7) + q * 4);
        a0 = di * v.x; a1 = di * v.y; a2 = di * v.z; a3 = di * v.w;
    }

    int e0 = rowptr[i], e1 = rowptr[i + 1];
    int deg = e1 - e0;
    int full = deg & ~7;
    int ee = e0 + full;
    for (int e = e0 + half * 4; e < ee; e += 8) {
        int2 r0 = ebuf2[e],     r1 = ebuf2[e + 1];
        int2 r2 = ebuf2[e + 2], r3 = ebuf2[e + 3];
        float4 w0 = *(const float4*)(zz + ((size_t)r0.x << 7) + q * 4);
        float4 w1 = *(const float4*)(zz + ((size_t)r1.x << 7) + q * 4);
        float4 w2 = *(const float4*)(zz + ((size_t)r2.x << 7) + q * 4);
        float4 w3 = *(const float4*)(zz + ((size_t)r3.x << 7) + q * 4);
        float n0 = __int_as_float(r0.y), n1 = __int_as_float(r1.y);
        float n2 = __int_as_float(r2.y), n3 = __int_as_float(r3.y);
        a0 += n0 * w0.x + n1 * w1.x + n2 * w2.x + n3 * w3.x;
        a1 += n0 * w0.y + n1 * w1.y + n2 * w2.y + n3 * w3.y;
        a2 += n0 * w0.z + n1 * w1.z + n2 * w2.z + n3 * w3.z;
        a3 += n0 * w0.w + n1 * w1.w + n2 * w2.w + n3 * w3.w;
    }
    for (int e = ee + half; e < e1; e += 2) {
        int2 r = ebuf2[e];
        float nm = __int_as_float(r.y);
        float4 w = *(const float4*)(zz + ((size_t)r.x << 7) + q * 4);
        a0 += nm * w.x; a1 += nm * w.y; a2 += nm * w.z; a3 += nm * w.w;
    }
    a0 += __shfl_xor(a0, 32);
    a1 += __shfl_xor(a1, 32);
    a2 += __shfl_xor(a2, 32);
    a3 += __shfl_xor(a3, 32);

    if (half == 0) {
        float4 b = *(const float4*)(bias + q * 4);
        float4 o;
        o.x = di * a0 + b.x;
        o.y = di * a1 + b.y;
        o.z = di * a2 + b.z;
        o.w = di * a3 + b.w;
        *(float4*)(out + (size_t)i * 128 + q * 4) = o;
    }
}

// ---------- pooling ----------
__global__ __launch_bounds__(128) void pool2_k(const float* __restrict__ h2,
                                               const int* __restrict__ batch,
                                               float* __restrict__ pooled)
{
    int g = blockIdx.x;
    int c = blockIdx.y;
    int f = threadIdx.x;
    int bs = lowerb(batch, NN, g);
    int be = lowerb(batch, NN, g + 1);
    int len = be - bs;
    int cs = bs + (int)(((long long)len * c) / PCH);
    int ce = bs + (int)(((long long)len * (c + 1)) / PCH);
    float a = 0.f;
    for (int i = cs; i < ce; i++) a += h2[(size_t)i * 128 + f];
    if (ce > cs) atomicAdd(&pooled[(size_t)g * 128 + f], a);
}

// ---------- fused fc + decoder + W3 transform ----------
__global__ __launch_bounds__(128) void fcdec_k(const float* __restrict__ pooled,
                                               const float* __restrict__ fcW,   // [128][64]
                                               const float* __restrict__ fcb,
                                               const float* __restrict__ decW,  // [64][128]
                                               const float* __restrict__ decb,
                                               const float* __restrict__ W3,    // [128][128]
                                               float* __restrict__ lat_out,
                                               float* __restrict__ zz)
{
    __shared__ float lat[64];
    __shared__ float zs[128];
    int g = blockIdx.x, c = threadIdx.x;
    if (c < 64) {
        const float* p = pooled + (size_t)g * 128;
        float a = fcb[c];
        #pragma unroll 8
        for (int k = 0; k < 128; k++) a = fmaf(p[k], fcW[(size_t)k * 64 + c], a);
        a = fmaxf(a, 0.f);
        lat[c] = a;
        lat_out[(size_t)g * 64 + c] = a;
    }
    __syncthreads();
    {
        float a = decb[c];
        #pragma unroll 8
        for (int k = 0; k < 64; k++) a = fmaf(lat[k], decW[(size_t)k * 128 + c], a);
        zs[c] = fmaxf(a, 0.f);
    }
    __syncthreads();
    float o = 0.f;
    #pragma unroll 8
    for (int k = 0; k < 128; k++) o = fmaf(zs[k], W3[(size_t)k * 128 + c], o);
    zz[(size_t)g * 128 + c] = o;
}

extern "C" void kernel_launch(void* const* d_in, const int* in_sizes, int n_in,
                              void* d_out, int out_size, void* d_ws, size_t ws_size,
                              hipStream_t stream)
{
    const float* x     = (const float*)d_in[0];
    const int*   ei    = (const int*)d_in[1];
    const int*   batch = (const int*)d_in[2];
    const float* W1  = (const float*)d_in[3];
    const float* b1  = (const float*)d_in[4];
    const float* W2  = (const float*)d_in[5];
    const float* b2  = (const float*)d_in[6];
    const float* fcW = (const float*)d_in[7];
    const float* fcb = (const float*)d_in[8];
    const float* decW= (const float*)d_in[9];
    const float* decb= (const float*)d_in[10];
    const float* W3  = (const float*)d_in[11];
    const float* b3  = (const float*)d_in[12];

    char* ws = (char*)d_ws;
    size_t off = 0;
    auto alloc = [&](size_t bytes) -> char* {
        char* p = ws + off;
        off = (off + bytes + 255) & ~(size_t)255;
        return p;
    };
    float* dinv     = (float*)alloc((size_t)NN * 4);
    int*   rowptr   = (int*)alloc((size_t)(NN + 1) * 4);
    int*   bcur     = (int*)alloc((size_t)NB * 4);
    int*   bbase    = (int*)alloc((size_t)NB * 4);
    int*   ebuf     = (int*)alloc((size_t)EE * 4);           // CSR src indices (4B/edge)
    int2*  ebuf2    = (int2*)alloc((size_t)EE * 8);          // {batch[src], dinv[src]}
    float* pooled   = (float*)alloc((size_t)GG * 128 * 4);
    float* zz       = (float*)alloc((size_t)GG * 128 * 4);
    f16x8* whi1     = (f16x8*)alloc(2048 * 16);              // W1 hi frags (32KB)
    f16x8* wlo1     = (f16x8*)alloc(2048 * 16);
    f16x8* whi2     = (f16x8*)alloc(2048 * 16);
    f16x8* wlo2     = (f16x8*)alloc(2048 * 16);
    __half* A       = (__half*)alloc((size_t)NN * 128 * 2);  // pre-scaled transformed feats (fp16)
    float* B        = (float*)alloc((size_t)NN * 128 * 4);   // hidden activations h (f32)
    // eraw (NB*CAP*8 = 12.8MB) aliases B (25.6MB): consumed by binB before aggh1 writes B
    int2*  eraw     = (int2*)B;

    float* recon_out = (float*)d_out;
    float* lat_out   = (float*)d_out + (size_t)NN * 128;

    prep_k<<<19, 256, 0, stream>>>(W1, W2, whi1, wlo1, whi2, wlo2, bcur, pooled);
    binA_k<<<ABLK, 512, 0, stream>>>(ei, bcur, eraw);
    scanb2_k<<<1, 512, 0, stream>>>(bcur, bbase, rowptr);
    binB_k<<<NB, 512, 0, stream>>>(eraw, bcur, bbase, rowptr, dinv, ebuf);
    pbb_k<<<(EE + 255) / 256, 256, 0, stream>>>(ebuf, batch, dinv, ebuf2);

    int gblk = (NN + 63) / 64;   // 782
    // conv1: A = dinv .* (x @ W1) (fp16) ; h1 = relu(dinv.*(agg(A)) + b1) -> B
    gemm_mfma3_k<<<gblk, 256, 0, stream>>>(x, whi1, wlo1, dinv, A, NN);
    aggh_k<<<NN, 64, 0, stream>>>(A, rowptr, ebuf, dinv, b1, B, 1);
    // conv2
    gemm_mfma3_k<<<gblk, 256, 0, stream>>>(B, whi2, wlo2, dinv, A, NN);
    aggh_k<<<NN, 64, 0, stream>>>(A, rowptr, ebuf, dinv, b2, B, 1);
    // pool + fused fc/dec (latent out) + conv3
    pool2_k<<<dim3(GG, PCH), 128, 0, stream>>>(B, batch, pooled);
    fcdec_k<<<GG, 128, 0, stream>>>(pooled, fcW, fcb, decW, decb, W3, lat_out, zz);
    agg_out_k<<<NN, 64, 0, stream>>>(zz, batch, rowptr, ebuf2, dinv,
                                     b3, recon_out);
}